// Round 2
// baseline (807.846 us; speedup 1.0000x reference)
//
#include <hip/hip_runtime.h>
#include <stdint.h>
#include <stddef.h>

// AttentionLayer2D: B=4, N=64*64=4096, C=512, Cfg=64
// out = gamma * softmax(g @ f^T) @ h + x   (per batch), residual in fp32.

#define B_ 4
#define N_ 4096
#define C_ 512
#define LOG2E 1.44269504088896f

typedef float f32x4 __attribute__((ext_vector_type(4)));
typedef float f32x2 __attribute__((ext_vector_type(2)));
typedef short s16x8 __attribute__((ext_vector_type(8)));

__device__ __forceinline__ unsigned short f2bf(float f) {
  unsigned u = __builtin_bit_cast(unsigned, f);
  u += 0x7FFFu + ((u >> 16) & 1u);   // RNE
  return (unsigned short)(u >> 16);
}

__device__ __forceinline__ unsigned cvt_pk_bf16(float lo, float hi) {
  unsigned r;
  asm("v_cvt_pk_bf16_f32 %0, %1, %2" : "=v"(r) : "v"(lo), "v"(hi));
  return r;
}

// ---------- weight transpose + bf16 convert: wT[n][k], n in [0,640), k in [0,512)
// rows 0..63 = kernel_f^T, 64..127 = kernel_g^T (scaled by log2e), 128..639 = kernel_h^T
__global__ void wt_kernel(const float* __restrict__ kf, const float* __restrict__ kg,
                          const float* __restrict__ kh, unsigned short* __restrict__ wT) {
  const int n = blockIdx.x;
  const float* src; int stride; float scl = 1.0f;
  if (n < 64)       { src = kf + n;         stride = 64;  }
  else if (n < 128) { src = kg + (n - 64);  stride = 64;  scl = LOG2E; }
  else              { src = kh + (n - 128); stride = 512; }
  for (int k = threadIdx.x; k < 512; k += blockDim.x)
    wT[(size_t)n * 512 + k] = f2bf(src[(size_t)k * stride] * scl);
}

// ---------- fused projection GEMM: [16384 x 512] @ [512 x 640] -> f, g, hT (bf16)
__global__ __launch_bounds__(256) void gemm_kernel(
    const float* __restrict__ x, const unsigned short* __restrict__ wT,
    const float* __restrict__ bf, const float* __restrict__ bg, const float* __restrict__ bh,
    unsigned short* __restrict__ fO, unsigned short* __restrict__ gO,
    unsigned short* __restrict__ hT)
{
  __shared__ unsigned short tile[64][64];
  const int tid = threadIdx.x;
  const int w = tid >> 6, l = tid & 63;
  const int l15 = l & 15, sub = l >> 4;
  const int mblock = blockIdx.x * 64;
  const int nblock = blockIdx.y * 64;

  const float* xrow = x + (size_t)(mblock + w * 16 + l15) * C_;

  f32x4 acc[4] = {{0,0,0,0},{0,0,0,0},{0,0,0,0},{0,0,0,0}};
  for (int kk = 0; kk < 512; kk += 32) {
    f32x4 a0 = *(const f32x4*)(xrow + kk + 8 * sub);
    f32x4 a1 = *(const f32x4*)(xrow + kk + 8 * sub + 4);
    s16x8 af;
    af[0] = (short)f2bf(a0[0]); af[1] = (short)f2bf(a0[1]);
    af[2] = (short)f2bf(a0[2]); af[3] = (short)f2bf(a0[3]);
    af[4] = (short)f2bf(a1[0]); af[5] = (short)f2bf(a1[1]);
    af[6] = (short)f2bf(a1[2]); af[7] = (short)f2bf(a1[3]);
#pragma unroll
    for (int t = 0; t < 4; ++t) {
      const int n = nblock + 16 * t + l15;
      const s16x8 bfr = *(const s16x8*)(wT + (size_t)n * 512 + kk + 8 * sub);
      acc[t] = __builtin_amdgcn_mfma_f32_16x16x32_bf16(af, bfr, acc[t], 0, 0, 0);
    }
  }

  const bool isF = (nblock == 0), isG = (nblock == 64);
#pragma unroll
  for (int t = 0; t < 4; ++t) {
    const int n = nblock + 16 * t + l15;
    const float bv = (n < 64) ? bf[n] : (n < 128 ? bg[n - 64] * LOG2E : bh[n - 128]);
#pragma unroll
    for (int v = 0; v < 4; ++v) {
      const int r = w * 16 + 4 * sub + v;
      const int c = 16 * t + l15;
      const unsigned short bv16 = f2bf(acc[t][v] + bv);
      if (isF || isG) tile[r][c] = bv16;
      else            tile[c][r] = bv16;
    }
  }
  __syncthreads();

  const int b = mblock >> 12;
  const int qb = mblock & 4095;
#pragma unroll
  for (int it = 0; it < 2; ++it) {
    const int u = tid + it * 256;
    const int rr = u >> 3, ch = u & 7;
    const s16x8 vdat = *(const s16x8*)&tile[rr][ch * 8];
    unsigned short* dst;
    if (isF)      dst = fO + (size_t)(mblock + rr) * 64 + ch * 8;
    else if (isG) dst = gO + (size_t)(mblock + rr) * 64 + ch * 8;
    else          dst = hT + ((size_t)b * 512 + (nblock - 128 + rr)) * 4096 + qb + ch * 8;
    *(s16x8*)dst = vdat;
  }
}

// ---------- flash attention, channel-split: block = 16 q-rows, wave w = channels [128w,128w+128)
// Swapped operands: S^T = mfma(f, g) -> lane holds S^T[j][q=l15]; row state scalar per lane.
// PV: o^T[c][q] = mfma(hT_row, P);  defer-max THR=8 (exp2 domain).
__global__ __launch_bounds__(256, 4) void attn_kernel(
    const unsigned short* __restrict__ fM, const unsigned short* __restrict__ gM,
    const unsigned short* __restrict__ hT, const float* __restrict__ x,
    const float* __restrict__ gamma, float* __restrict__ out)
{
  __shared__ float olds[4][16][136];     // epilogue transpose staging (34.8 KB)
  const int tid = threadIdx.x;
  const int w = tid >> 6, l = tid & 63;
  const int l15 = l & 15, sub = l >> 4;
  // bijective XCD swizzle: physical p -> logical L so each XCD gets a contiguous 128-block chunk
  const int p = blockIdx.x;
  const int L = (p & 7) * 128 + (p >> 3);
  const int b = L >> 8;
  const int qbase = (L & 255) * 16;
  const int cw0 = w * 128;

  // B-operand (g rows = q cols), hoisted for whole loop
  const unsigned short* grow = gM + ((size_t)b * 4096 + qbase + l15) * 64;
  const s16x8 ga0 = *(const s16x8*)(grow + 8 * sub);
  const s16x8 ga1 = *(const s16x8*)(grow + 32 + 8 * sub);

  const unsigned short* fbase = fM + (size_t)b * 4096 * 64;
  const unsigned short* hbase = hT + ((size_t)b * 512 + cw0 + l15) * 4096;

  float m = -1e30f, lsum = 0.f;
  f32x4 o[8];
#pragma unroll
  for (int t = 0; t < 8; ++t) o[t] = (f32x4){0, 0, 0, 0};

  const int src0 = l15 + 16 * ((2 * sub) & 3);
  const int src1 = l15 + 16 * ((2 * sub + 1) & 3);

  for (int jb = 0; jb < 128; ++jb) {
    const int j0 = jb * 32;
    // QK^T (swapped): A = f rows (j), B = g rows (q)
    const unsigned short* f0 = fbase + (size_t)(j0 + l15) * 64 + 8 * sub;
    const unsigned short* f1 = f0 + 16 * 64;
    const s16x8 fb00 = *(const s16x8*)(f0);
    const s16x8 fb01 = *(const s16x8*)(f0 + 32);
    const s16x8 fb10 = *(const s16x8*)(f1);
    const s16x8 fb11 = *(const s16x8*)(f1 + 32);
    f32x4 st0 = {0,0,0,0}, st1 = {0,0,0,0};
    st0 = __builtin_amdgcn_mfma_f32_16x16x32_bf16(fb00, ga0, st0, 0, 0, 0);
    st0 = __builtin_amdgcn_mfma_f32_16x16x32_bf16(fb01, ga1, st0, 0, 0, 0);
    st1 = __builtin_amdgcn_mfma_f32_16x16x32_bf16(fb10, ga0, st1, 0, 0, 0);
    st1 = __builtin_amdgcn_mfma_f32_16x16x32_bf16(fb11, ga1, st1, 0, 0, 0);
    // lane: st0[v] = S'[j0+4*sub+v][q=l15], st1[v] = S'[j0+16+4*sub+v][q=l15]  (log2 domain)

    // tile max over j (in-register + 2 shfl)
    float tmx = fmaxf(fmaxf(fmaxf(st0[0], st0[1]), fmaxf(st0[2], st0[3])),
                      fmaxf(fmaxf(st1[0], st1[1]), fmaxf(st1[2], st1[3])));
    tmx = fmaxf(tmx, __shfl_xor(tmx, 16));
    tmx = fmaxf(tmx, __shfl_xor(tmx, 32));

    if (__any(tmx > m + 8.0f)) {           // defer-max, THR=8 (p bounded by 2^8)
      const float mn = fmaxf(m, tmx);
      const float sc = __builtin_amdgcn_exp2f(m - mn);
      lsum *= sc; m = mn;
#pragma unroll
      for (int t = 0; t < 8; ++t) o[t] *= sc;
    }

    float p0[4], p1[4];
#pragma unroll
    for (int v = 0; v < 4; ++v) {
      p0[v] = __builtin_amdgcn_exp2f(st0[v] - m);
      p1[v] = __builtin_amdgcn_exp2f(st1[v] - m);
    }
    float rs = (p0[0] + p0[1]) + (p0[2] + p0[3]) + (p1[0] + p1[1]) + (p1[2] + p1[3]);
    rs += __shfl_xor(rs, 16);
    rs += __shfl_xor(rs, 32);
    lsum += rs;

    // pack P to bf16 pairs and redistribute to B-fragment layout (8 shfl + 4 select)
    const unsigned pk0 = cvt_pk_bf16(p0[0], p0[1]);   // j-off 4*sub+0,1
    const unsigned pk1 = cvt_pk_bf16(p0[2], p0[3]);   // j-off 4*sub+2,3
    const unsigned pk2 = cvt_pk_bf16(p1[0], p1[1]);   // j-off 16+4*sub+0,1
    const unsigned pk3 = cvt_pk_bf16(p1[2], p1[3]);   // j-off 16+4*sub+2,3
    const bool lo = (sub < 2);
    unsigned pw0 = lo ? __shfl(pk0, src0) : __shfl(pk2, src0);
    unsigned pw1 = lo ? __shfl(pk1, src0) : __shfl(pk3, src0);
    unsigned pw2 = lo ? __shfl(pk0, src1) : __shfl(pk2, src1);
    unsigned pw3 = lo ? __shfl(pk1, src1) : __shfl(pk3, src1);
    // NB: both shfl operands are evaluated for all lanes (no divergence): force via select
    struct { unsigned u[4]; } paw;
    paw.u[0] = pw0; paw.u[1] = pw1; paw.u[2] = pw2; paw.u[3] = pw3;
    const s16x8 pa = __builtin_bit_cast(s16x8, paw);

    // PV: o^T[c][q] += hT[c][j] * P[j][q];  A = hT row (c = cw0+16t+l15), B = pa
#pragma unroll
    for (int t = 0; t < 8; ++t) {
      const s16x8 hb = *(const s16x8*)(hbase + (size_t)t * 16 * 4096 + j0 + 8 * sub);
      o[t] = __builtin_amdgcn_mfma_f32_16x16x32_bf16(hb, pa, o[t], 0, 0, 0);
    }
  }

  // epilogue: scale by gamma/lsum, transpose o^T -> [q][c] via LDS, coalesced residual write
  const float gs = gamma[0] / lsum;       // lane's q = l15 (uniform across subs)
#pragma unroll
  for (int t = 0; t < 8; ++t) {
    f32x4 val = o[t] * gs;
    *(f32x4*)&olds[w][l15][16 * t + 4 * sub] = val;
  }
  const float* xb = x + ((size_t)b * 4096 + qbase) * 512 + cw0;
  float* ob = out + ((size_t)b * 4096 + qbase) * 512 + cw0;
#pragma unroll
  for (int q = 0; q < 16; ++q) {
    const f32x2 sv = *(const f32x2*)&olds[w][q][2 * l];
    const f32x2 xv = *(const f32x2*)(xb + (size_t)q * 512 + 2 * l);
    f32x2 r; r.x = sv.x + xv.x; r.y = sv.y + xv.y;
    *(f32x2*)(ob + (size_t)q * 512 + 2 * l) = r;
  }
}

extern "C" void kernel_launch(void* const* d_in, const int* in_sizes, int n_in,
                              void* d_out, int out_size, void* d_ws, size_t ws_size,
                              hipStream_t stream) {
  const float* x     = (const float*)d_in[0];
  const float* kf    = (const float*)d_in[1];
  const float* kg    = (const float*)d_in[2];
  const float* kh    = (const float*)d_in[3];
  const float* bf    = (const float*)d_in[4];
  const float* bg    = (const float*)d_in[5];
  const float* bh    = (const float*)d_in[6];
  const float* gamma = (const float*)d_in[7];
  float* out = (float*)d_out;

  // workspace layout (bytes): f [0,2M) g [2M,4M) hT [4M,20M) wT [20M,20.625M)
  char* ws = (char*)d_ws;
  unsigned short* fO = (unsigned short*)(ws);
  unsigned short* gO = (unsigned short*)(ws + (2u << 20));
  unsigned short* hT = (unsigned short*)(ws + (4u << 20));
  unsigned short* wT = (unsigned short*)(ws + (20u << 20));

  hipLaunchKernelGGL(wt_kernel,   dim3(640),     dim3(256), 0, stream, kf, kg, kh, wT);
  hipLaunchKernelGGL(gemm_kernel, dim3(256, 10), dim3(256), 0, stream,
                     x, wT, bf, bg, bh, fO, gO, hT);
  hipLaunchKernelGGL(attn_kernel, dim3(1024),    dim3(256), 0, stream,
                     fO, gO, hT, x, gamma, out);
}

// Round 3
// 307.431 us; speedup vs baseline: 2.6277x; 2.6277x over previous
//
#include <hip/hip_runtime.h>
#include <stdint.h>
#include <stddef.h>

// AttentionLayer2D: B=4, N=64*64=4096, C=512, Cfg=64
// out = gamma * softmax(g @ f^T) @ h + x   (per batch), residual in fp32.

#define B_ 4
#define N_ 4096
#define C_ 512
#define LOG2E 1.44269504088896f

typedef float f32x4 __attribute__((ext_vector_type(4)));
typedef short s16x8 __attribute__((ext_vector_type(8)));
typedef unsigned u32x2 __attribute__((ext_vector_type(2)));

__device__ __forceinline__ unsigned short f2bf(float f) {
  unsigned u = __builtin_bit_cast(unsigned, f);
  u += 0x7FFFu + ((u >> 16) & 1u);   // RNE
  return (unsigned short)(u >> 16);
}

__device__ __forceinline__ unsigned cvt_pk_bf16(float lo, float hi) {
  unsigned r;
  asm("v_cvt_pk_bf16_f32 %0, %1, %2" : "=v"(r) : "v"(lo), "v"(hi));
  return r;
}

// ---------- weight transpose + bf16 convert: wT[n][k], n in [0,640), k in [0,512)
// rows 0..63 = kernel_f^T, 64..127 = kernel_g^T (scaled by log2e), 128..639 = kernel_h^T
__global__ void wt_kernel(const float* __restrict__ kf, const float* __restrict__ kg,
                          const float* __restrict__ kh, unsigned short* __restrict__ wT) {
  const int n = blockIdx.x;
  const float* src; int stride; float scl = 1.0f;
  if (n < 64)       { src = kf + n;         stride = 64;  }
  else if (n < 128) { src = kg + (n - 64);  stride = 64;  scl = LOG2E; }
  else              { src = kh + (n - 128); stride = 512; }
  for (int k = threadIdx.x; k < 512; k += blockDim.x)
    wT[(size_t)n * 512 + k] = f2bf(src[(size_t)k * stride] * scl);
}

// ---------- projection GEMM: x[16384x512] @ wT^T -> f,g (bf16 [row][64]) and
// hP panels: hP[b][j>>5][c][j&31] (each 512x32 panel contiguous, 32KB).
// Block = 256 thr (4 waves), 64 rows; A-frags in registers (x read ONCE); loop 10 n-panels.
__global__ __launch_bounds__(256) void gemm_kernel(
    const float* __restrict__ x, const unsigned short* __restrict__ wT,
    const float* __restrict__ bfv, const float* __restrict__ bgv, const float* __restrict__ bhv,
    unsigned short* __restrict__ fO, unsigned short* __restrict__ gO,
    unsigned short* __restrict__ hP)
{
  __shared__ __align__(16) float xstg[64 * 132];   // 33.8 KB; later overlaid by ushort tile[64*64]
  const int tid = threadIdx.x;
  const int w = tid >> 6, l = tid & 63;
  const int l15 = l & 15, sub = l >> 4;
  const int mb = blockIdx.x;            // 0..255, rows mb*64
  const int bb = mb >> 6;               // batch
  const int qb = (mb * 64) & 4095;      // row-in-batch base

  // ---- load A fragments to registers: 4 staging rounds of k=128
  s16x8 afr[16];
#pragma unroll
  for (int sr = 0; sr < 4; ++sr) {
    const float* xsrc = x + (size_t)(mb * 64) * 512 + sr * 128;
#pragma unroll
    for (int k = 0; k < 8; ++k) {
      const int ch = tid + k * 256;               // 0..2047
      const int row = ch >> 5, col = (ch & 31) * 4;
      const f32x4 v = *(const f32x4*)(xsrc + (size_t)row * 512 + col);
      *(f32x4*)&xstg[row * 132 + col] = v;
    }
    __syncthreads();
#pragma unroll
    for (int kk = 0; kk < 4; ++kk) {
      const float* ap = &xstg[(w * 16 + l15) * 132 + kk * 32 + sub * 8];
      const f32x4 a0 = *(const f32x4*)ap;
      const f32x4 a1 = *(const f32x4*)(ap + 4);
      s16x8 af;
      af[0] = (short)f2bf(a0[0]); af[1] = (short)f2bf(a0[1]);
      af[2] = (short)f2bf(a0[2]); af[3] = (short)f2bf(a0[3]);
      af[4] = (short)f2bf(a1[0]); af[5] = (short)f2bf(a1[1]);
      af[6] = (short)f2bf(a1[2]); af[7] = (short)f2bf(a1[3]);
      afr[sr * 4 + kk] = af;
    }
    __syncthreads();
  }

  unsigned short* tile = (unsigned short*)xstg;   // 64x64 ushorts (8 KB) overlay

  for (int nb = 0; nb < 10; ++nb) {
    f32x4 acc[4] = {{0,0,0,0},{0,0,0,0},{0,0,0,0},{0,0,0,0}};
#pragma unroll
    for (int ks = 0; ks < 16; ++ks) {
#pragma unroll
      for (int t = 0; t < 4; ++t) {
        const s16x8 bfr = *(const s16x8*)(wT + (size_t)(nb * 64 + 16 * t + l15) * 512
                                              + ks * 32 + sub * 8);
        acc[t] = __builtin_amdgcn_mfma_f32_16x16x32_bf16(afr[ks], bfr, acc[t], 0, 0, 0);
      }
    }
    __syncthreads();   // previous tile reads (or xstg frag reads) complete
#pragma unroll
    for (int t = 0; t < 4; ++t) {
      const int n = nb * 64 + 16 * t + l15;
      const float bv = (n < 64) ? bfv[n] : (n < 128 ? bgv[n - 64] * LOG2E : bhv[n - 128]);
#pragma unroll
      for (int v = 0; v < 4; ++v) {
        const int r = w * 16 + 4 * sub + v;   // local row
        const int c = 16 * t + l15;           // local col
        const unsigned short val = f2bf(acc[t][v] + bv);
        if (nb <= 1) tile[r * 64 + c] = val;  // f/g: [row][col]
        else         tile[c * 64 + r] = val;  // h: [c][j]
      }
    }
    __syncthreads();
#pragma unroll
    for (int it = 0; it < 2; ++it) {
      const int u = tid + it * 256;
      const int rr = u >> 3, chh = u & 7;
      const s16x8 vdat = *(const s16x8*)&tile[rr * 64 + chh * 8];
      if (nb == 0)      *(s16x8*)(fO + (size_t)(mb * 64 + rr) * 64 + chh * 8) = vdat;
      else if (nb == 1) *(s16x8*)(gO + (size_t)(mb * 64 + rr) * 64 + chh * 8) = vdat;
      else {
        const int j8 = qb + chh * 8;          // 8 consecutive j within one 32-panel
        *(s16x8*)(hP + (((size_t)bb * 128 + (j8 >> 5)) * 512 + (nb * 64 - 128 + rr)) * 32
                      + (j8 & 31)) = vdat;
      }
    }
  }
}

// ---------- flash attention: block = 64 q-rows, 4 waves.
// QK^T q-split (wave w owns q-tile w); P shared via LDS; PV c-split (wave w owns c [128w,128w+128)).
// h panel [512 c][32 j] staged to LDS per jb (coalesced, T14 issue-early/write-late).
__global__ __launch_bounds__(256, 1) void attn_kernel(
    const unsigned short* __restrict__ fM, const unsigned short* __restrict__ gM,
    const unsigned short* __restrict__ hP, const float* __restrict__ x,
    const float* __restrict__ gamma, float* __restrict__ out)
{
  __shared__ __align__(16) unsigned short hbuf[512 * 40];  // stride 80B/row; 40 KB (epilogue: float olds[16*516])
  __shared__ __align__(16) unsigned short fbuf[32 * 72];   // stride 144B/row; 4.6 KB
  __shared__ __align__(16) unsigned pbuf32[64 * 16];       // P [64 q][32 j] bf16 = 4 KB
  __shared__ float scl[64];
  __shared__ float lsumT[64];

  const int tid = threadIdx.x;
  const int w = tid >> 6, l = tid & 63;
  const int l15 = l & 15, sub = l >> 4;
  // bijective XCD swizzle: 256 blocks, XCD k gets logical [32k,32k+32) -> 2 XCDs per batch
  const int p = blockIdx.x;
  const int L = (p & 7) * 32 + (p >> 3);
  const int b = L >> 6;
  const int qbase = (L & 63) * 64;

  // B-operand for QK^T: g rows of this wave's q-tile (qt = w), hoisted
  const unsigned short* grow = gM + ((size_t)b * 4096 + qbase + w * 16 + l15) * 64;
  const s16x8 ga0 = *(const s16x8*)(grow + 8 * sub);
  const s16x8 ga1 = *(const s16x8*)(grow + 32 + 8 * sub);

  const unsigned short* hPb = hP + (size_t)b * 128 * 16384;
  const unsigned short* fMb = fM + (size_t)b * 4096 * 64;

  float mrun = -1e30f, lsum = 0.f;
  f32x4 o[8][4];
#pragma unroll
  for (int ct = 0; ct < 8; ++ct)
#pragma unroll
    for (int qt = 0; qt < 4; ++qt) o[ct][qt] = (f32x4){0, 0, 0, 0};

  // ---- prologue: stage panel jb=0
  {
    const s16x8* hsrc = (const s16x8*)(hPb);
#pragma unroll
    for (int k = 0; k < 8; ++k) {
      const int ch = tid + k * 256;
      const s16x8 v = hsrc[ch];
      *(s16x8*)&hbuf[(ch >> 2) * 40 + (ch & 3) * 8] = v;
    }
    const s16x8 fv = ((const s16x8*)fMb)[tid];
    *(s16x8*)&fbuf[(tid >> 3) * 72 + (tid & 7) * 8] = fv;
  }
  __syncthreads();

  for (int jb = 0; jb < 128; ++jb) {
    // (1) issue next panel's global loads early (hide under compute)
    const int jn = (jb < 127) ? jb + 1 : 127;
    s16x8 hstg[8]; s16x8 fstg;
    {
      const s16x8* hsrc = (const s16x8*)(hPb + (size_t)jn * 16384);
#pragma unroll
      for (int k = 0; k < 8; ++k) hstg[k] = hsrc[tid + k * 256];
      fstg = ((const s16x8*)(fMb + (size_t)jn * 32 * 64))[tid];
    }

    // (2) QK^T for this wave's q-tile (qt = w), all 32 j
    f32x4 st0 = {0,0,0,0}, st1 = {0,0,0,0};
    {
      const s16x8 fa00 = *(const s16x8*)&fbuf[(l15)      * 72 +      sub * 8];
      const s16x8 fa01 = *(const s16x8*)&fbuf[(l15)      * 72 + 32 + sub * 8];
      const s16x8 fa10 = *(const s16x8*)&fbuf[(16 + l15) * 72 +      sub * 8];
      const s16x8 fa11 = *(const s16x8*)&fbuf[(16 + l15) * 72 + 32 + sub * 8];
      st0 = __builtin_amdgcn_mfma_f32_16x16x32_bf16(fa00, ga0, st0, 0, 0, 0);
      st0 = __builtin_amdgcn_mfma_f32_16x16x32_bf16(fa01, ga1, st0, 0, 0, 0);
      st1 = __builtin_amdgcn_mfma_f32_16x16x32_bf16(fa10, ga0, st1, 0, 0, 0);
      st1 = __builtin_amdgcn_mfma_f32_16x16x32_bf16(fa11, ga1, st1, 0, 0, 0);
    }
    // lane: st0[v] = S'[j0+4sub+v][q=w*16+l15], st1[v] = +16   (log2 domain)

    // (3) online softmax (owner of qt=w); defer-max THR=8
    float tmx = fmaxf(fmaxf(fmaxf(st0[0], st0[1]), fmaxf(st0[2], st0[3])),
                      fmaxf(fmaxf(st1[0], st1[1]), fmaxf(st1[2], st1[3])));
    tmx = fmaxf(tmx, __shfl_xor(tmx, 16));
    tmx = fmaxf(tmx, __shfl_xor(tmx, 32));
    float sc = 1.0f;
    if (__any(tmx > mrun + 8.0f)) {
      const float mn = fmaxf(mrun, tmx);
      sc = __builtin_amdgcn_exp2f(mrun - mn);
      mrun = mn; lsum *= sc;
    }
    float p0[4], p1[4];
#pragma unroll
    for (int v = 0; v < 4; ++v) {
      p0[v] = __builtin_amdgcn_exp2f(st0[v] - mrun);
      p1[v] = __builtin_amdgcn_exp2f(st1[v] - mrun);
    }
    float rs = (p0[0] + p0[1]) + (p0[2] + p0[3]) + (p1[0] + p1[1]) + (p1[2] + p1[3]);
    rs += __shfl_xor(rs, 16);
    rs += __shfl_xor(rs, 32);
    lsum += rs;

    const unsigned pk0 = cvt_pk_bf16(p0[0], p0[1]);   // j = 4sub+0,1
    const unsigned pk1 = cvt_pk_bf16(p0[2], p0[3]);   // j = 4sub+2,3
    const unsigned pk2 = cvt_pk_bf16(p1[0], p1[1]);   // j = 16+4sub+0,1
    const unsigned pk3 = cvt_pk_bf16(p1[2], p1[3]);   // j = 16+4sub+2,3
    const int qown = w * 16 + l15;
    *(u32x2*)&pbuf32[qown * 16 + 2 * sub]     = (u32x2){pk0, pk1};
    *(u32x2*)&pbuf32[qown * 16 + 8 + 2 * sub] = (u32x2){pk2, pk3};
    if (sub == 0) scl[qown] = sc;
    __syncthreads();   // (4) P + scl ready

    // (5) PV: rescale + 8 c-tiles x 4 q-tiles
    float sc4[4];
#pragma unroll
    for (int qt = 0; qt < 4; ++qt) sc4[qt] = scl[qt * 16 + l15];
    if (__any(fminf(fminf(sc4[0], sc4[1]), fminf(sc4[2], sc4[3])) < 1.0f)) {
#pragma unroll
      for (int ct = 0; ct < 8; ++ct)
#pragma unroll
        for (int qt = 0; qt < 4; ++qt) o[ct][qt] *= sc4[qt];
    }
    s16x8 pa[4];
#pragma unroll
    for (int qt = 0; qt < 4; ++qt)
      pa[qt] = *(const s16x8*)((const unsigned short*)pbuf32 + (qt * 16 + l15) * 32 + sub * 8);
#pragma unroll
    for (int ct = 0; ct < 8; ++ct) {
      const s16x8 hbv = *(const s16x8*)&hbuf[(w * 128 + ct * 16 + l15) * 40 + sub * 8];
#pragma unroll
      for (int qt = 0; qt < 4; ++qt)
        o[ct][qt] = __builtin_amdgcn_mfma_f32_16x16x32_bf16(hbv, pa[qt], o[ct][qt], 0, 0, 0);
    }
    __syncthreads();   // (6) all reads of hbuf/fbuf/pbuf done

    // (7) write next panel to LDS (vmcnt wait auto-inserted)
#pragma unroll
    for (int k = 0; k < 8; ++k) {
      const int ch = tid + k * 256;
      *(s16x8*)&hbuf[(ch >> 2) * 40 + (ch & 3) * 8] = hstg[k];
    }
    *(s16x8*)&fbuf[(tid >> 3) * 72 + (tid & 7) * 8] = fstg;
    __syncthreads();   // (8) buffers ready
  }

  // ---- epilogue: out = gamma/lsum * o^T + x, via LDS transpose (reuse hbuf)
  if (sub == 0) lsumT[w * 16 + l15] = lsum;
  __syncthreads();
  const float gam = gamma[0];
  float* olds = (float*)hbuf;           // 16 x 516 floats = 33 KB
#pragma unroll
  for (int qt = 0; qt < 4; ++qt) {
    const float gs = gam / lsumT[qt * 16 + l15];
#pragma unroll
    for (int ct = 0; ct < 8; ++ct) {
      const f32x4 vv = o[ct][qt] * gs;
      *(f32x4*)&olds[l15 * 516 + w * 128 + ct * 16 + 4 * sub] = vv;
    }
    __syncthreads();
    const int r = tid >> 4, c0 = (tid & 15) * 4;
    const float* xr  = x   + ((size_t)b * 4096 + qbase + qt * 16 + r) * 512;
    float*       orw = out + ((size_t)b * 4096 + qbase + qt * 16 + r) * 512;
#pragma unroll
    for (int i = 0; i < 8; ++i) {
      const int cc = c0 + i * 64;
      const f32x4 vv = *(const f32x4*)&olds[r * 516 + cc];
      const f32x4 xv = *(const f32x4*)(xr + cc);
      *(f32x4*)(orw + cc) = vv + xv;
    }
    __syncthreads();
  }
}

extern "C" void kernel_launch(void* const* d_in, const int* in_sizes, int n_in,
                              void* d_out, int out_size, void* d_ws, size_t ws_size,
                              hipStream_t stream) {
  const float* x     = (const float*)d_in[0];
  const float* kf    = (const float*)d_in[1];
  const float* kg    = (const float*)d_in[2];
  const float* kh    = (const float*)d_in[3];
  const float* bf    = (const float*)d_in[4];
  const float* bg    = (const float*)d_in[5];
  const float* bh    = (const float*)d_in[6];
  const float* gamma = (const float*)d_in[7];
  float* out = (float*)d_out;

  // workspace layout (bytes): f [0,2M) g [2M,4M) hP [4M,20M) wT [20M,20.625M)
  char* ws = (char*)d_ws;
  unsigned short* fO = (unsigned short*)(ws);
  unsigned short* gO = (unsigned short*)(ws + (2u << 20));
  unsigned short* hP = (unsigned short*)(ws + (4u << 20));
  unsigned short* wT = (unsigned short*)(ws + (20u << 20));

  hipLaunchKernelGGL(wt_kernel,   dim3(640), dim3(256), 0, stream, kf, kg, kh, wT);
  hipLaunchKernelGGL(gemm_kernel, dim3(256), dim3(256), 0, stream,
                     x, wT, bf, bg, bh, fO, gO, hP);
  hipLaunchKernelGGL(attn_kernel, dim3(256), dim3(256), 0, stream,
                     fO, gO, hP, x, gamma, out);
}

// Round 4
// 236.659 us; speedup vs baseline: 3.4135x; 1.2990x over previous
//
#include <hip/hip_runtime.h>
#include <stdint.h>
#include <stddef.h>

// AttentionLayer2D: B=4, N=64*64=4096, C=512, Cfg=64
// out = gamma * softmax(g @ f^T) @ h + x   (per batch), residual in fp32.

#define LOG2E 1.44269504088896f

typedef float f32x4 __attribute__((ext_vector_type(4)));
typedef short s16x8 __attribute__((ext_vector_type(8)));
typedef unsigned u32x2 __attribute__((ext_vector_type(2)));

__device__ __forceinline__ unsigned short f2bf(float f) {
  unsigned u = __builtin_bit_cast(unsigned, f);
  u += 0x7FFFu + ((u >> 16) & 1u);   // RNE
  return (unsigned short)(u >> 16);
}

__device__ __forceinline__ unsigned cvt_pk_bf16(float lo, float hi) {
  unsigned r;
  asm("v_cvt_pk_bf16_f32 %0, %1, %2" : "=v"(r) : "v"(lo), "v"(hi));
  return r;
}

// ---------- weight transpose + bf16 convert: wT[n][k], n in [0,640), k in [0,512)
__global__ void wt_kernel(const float* __restrict__ kf, const float* __restrict__ kg,
                          const float* __restrict__ kh, unsigned short* __restrict__ wT) {
  const int n = blockIdx.x;
  const float* src; int stride; float scl = 1.0f;
  if (n < 64)       { src = kf + n;         stride = 64;  }
  else if (n < 128) { src = kg + (n - 64);  stride = 64;  scl = LOG2E; }
  else              { src = kh + (n - 128); stride = 512; }
  for (int k = threadIdx.x; k < 512; k += blockDim.x)
    wT[(size_t)n * 512 + k] = f2bf(src[(size_t)k * stride] * scl);
}

// ---------- projection GEMM: x[16384x512] @ wT^T -> f,g (bf16 [row][64]) and
// hP panels: hP[b][j>>5][c][j&31] (each 512x32 panel contiguous, 32KB).
__global__ __launch_bounds__(256) void gemm_kernel(
    const float* __restrict__ x, const unsigned short* __restrict__ wT,
    const float* __restrict__ bfv, const float* __restrict__ bgv, const float* __restrict__ bhv,
    unsigned short* __restrict__ fO, unsigned short* __restrict__ gO,
    unsigned short* __restrict__ hP)
{
  __shared__ __align__(16) float xstg[64 * 132];
  const int tid = threadIdx.x;
  const int w = tid >> 6, l = tid & 63;
  const int l15 = l & 15, sub = l >> 4;
  const int mb = blockIdx.x;
  const int bb = mb >> 6;
  const int qb = (mb * 64) & 4095;

  s16x8 afr[16];
#pragma unroll
  for (int sr = 0; sr < 4; ++sr) {
    const float* xsrc = x + (size_t)(mb * 64) * 512 + sr * 128;
#pragma unroll
    for (int k = 0; k < 8; ++k) {
      const int ch = tid + k * 256;
      const int row = ch >> 5, col = (ch & 31) * 4;
      const f32x4 v = *(const f32x4*)(xsrc + (size_t)row * 512 + col);
      *(f32x4*)&xstg[row * 132 + col] = v;
    }
    __syncthreads();
#pragma unroll
    for (int kk = 0; kk < 4; ++kk) {
      const float* ap = &xstg[(w * 16 + l15) * 132 + kk * 32 + sub * 8];
      const f32x4 a0 = *(const f32x4*)ap;
      const f32x4 a1 = *(const f32x4*)(ap + 4);
      s16x8 af;
      af[0] = (short)f2bf(a0[0]); af[1] = (short)f2bf(a0[1]);
      af[2] = (short)f2bf(a0[2]); af[3] = (short)f2bf(a0[3]);
      af[4] = (short)f2bf(a1[0]); af[5] = (short)f2bf(a1[1]);
      af[6] = (short)f2bf(a1[2]); af[7] = (short)f2bf(a1[3]);
      afr[sr * 4 + kk] = af;
    }
    __syncthreads();
  }

  unsigned short* tile = (unsigned short*)xstg;

  for (int nb = 0; nb < 10; ++nb) {
    f32x4 acc[4] = {{0,0,0,0},{0,0,0,0},{0,0,0,0},{0,0,0,0}};
#pragma unroll
    for (int ks = 0; ks < 16; ++ks) {
#pragma unroll
      for (int t = 0; t < 4; ++t) {
        const s16x8 bfr = *(const s16x8*)(wT + (size_t)(nb * 64 + 16 * t + l15) * 512
                                              + ks * 32 + sub * 8);
        acc[t] = __builtin_amdgcn_mfma_f32_16x16x32_bf16(afr[ks], bfr, acc[t], 0, 0, 0);
      }
    }
    __syncthreads();
#pragma unroll
    for (int t = 0; t < 4; ++t) {
      const int n = nb * 64 + 16 * t + l15;
      const float bv = (n < 64) ? bfv[n] : (n < 128 ? bgv[n - 64] * LOG2E : bhv[n - 128]);
#pragma unroll
      for (int v = 0; v < 4; ++v) {
        const int r = w * 16 + 4 * sub + v;
        const int c = 16 * t + l15;
        const unsigned short val = f2bf(acc[t][v] + bv);
        if (nb <= 1) tile[r * 64 + c] = val;
        else         tile[c * 64 + r] = val;
      }
    }
    __syncthreads();
#pragma unroll
    for (int it = 0; it < 2; ++it) {
      const int u = tid + it * 256;
      const int rr = u >> 3, chh = u & 7;
      const s16x8 vdat = *(const s16x8*)&tile[rr * 64 + chh * 8];
      if (nb == 0)      *(s16x8*)(fO + (size_t)(mb * 64 + rr) * 64 + chh * 8) = vdat;
      else if (nb == 1) *(s16x8*)(gO + (size_t)(mb * 64 + rr) * 64 + chh * 8) = vdat;
      else {
        const int j8 = qb + chh * 8;
        *(s16x8*)(hP + (((size_t)bb * 128 + (j8 >> 5)) * 512 + (nb * 64 - 128 + rr)) * 32
                      + (j8 & 31)) = vdat;
      }
    }
  }
}

// ---------- flash attention: block = 64 q-rows, 8 waves = 2 j-streams x 4 waves.
// Stream s (waves 4s..4s+3): panels [64s, 64s+64). Within stream: wave ws owns q-tile ws
// for QK^T/softmax, c-slice [128*ws,128*ws+128) for PV. h/f direct from L2 into regs;
// only P goes through LDS. End: merge the two streams' (m,l,o) in LDS.
__global__ __launch_bounds__(512, 2) void attn_kernel(
    const unsigned short* __restrict__ fM, const unsigned short* __restrict__ gM,
    const unsigned short* __restrict__ hP, const float* __restrict__ x,
    const float* __restrict__ gamma, float* __restrict__ out)
{
  __shared__ __align__(16) char smem[66048];   // main: pbuf[2][4KB]+scl; epi: 2 x [16][516] f32
  __shared__ float mfin[2][64];
  __shared__ float lfin[2][64];
  unsigned* pbuf = (unsigned*)smem;            // [2][64*16] u32
  float* sclp    = (float*)(smem + 8192);      // [2][64]

  const int tid = threadIdx.x;
  const int w = tid >> 6, l = tid & 63;
  const int l15 = l & 15, sub = l >> 4;
  const int s = w >> 2, ws = w & 3;

  // bijective XCD swizzle: 256 blocks -> XCD k gets logical [32k, 32k+32)
  const int p = blockIdx.x;
  const int L = (p & 7) * 32 + (p >> 3);
  const int b = L >> 6;
  const int qbase = (L & 63) * 64;

  // QK^T B-operand: g rows of this wave's q-tile, hoisted for entire kernel
  const unsigned short* grow = gM + ((size_t)b * 4096 + qbase + ws * 16 + l15) * 64;
  const s16x8 ga0 = *(const s16x8*)(grow + 8 * sub);
  const s16x8 ga1 = *(const s16x8*)(grow + 32 + 8 * sub);

  const unsigned short* hPb = hP + (size_t)b * 128 * 16384;
  const unsigned short* fMb = fM + (size_t)b * 4096 * 64;
  const unsigned short* hlane = hPb + (size_t)(ws * 128 + l15) * 32 + sub * 8;
  unsigned* pb = pbuf + s * 1024;
  float* sc_arr = sclp + s * 64;
  const int qown = ws * 16 + l15;

  // prologue: f fragments for first panel
  const int jb0 = s * 64;
  const unsigned short* f0p = fMb + (size_t)(jb0 * 32 + l15) * 64 + 8 * sub;
  s16x8 fr00 = *(const s16x8*)(f0p);
  s16x8 fr01 = *(const s16x8*)(f0p + 32);
  s16x8 fr10 = *(const s16x8*)(f0p + 1024);
  s16x8 fr11 = *(const s16x8*)(f0p + 1024 + 32);

  float mrun = -1e30f, lsum = 0.f;
  f32x4 o[8][4];
#pragma unroll
  for (int ct = 0; ct < 8; ++ct)
#pragma unroll
    for (int qt = 0; qt < 4; ++qt) o[ct][qt] = (f32x4){0, 0, 0, 0};

  for (int it = 0; it < 64; ++it) {
    const int jb = s * 64 + it;
    // issue h loads for CURRENT panel (L2-hot; latency hidden by QK^T+softmax+barrier)
    s16x8 hreg[8];
    const unsigned short* hp = hlane + (size_t)jb * 16384;
#pragma unroll
    for (int ct = 0; ct < 8; ++ct) hreg[ct] = *(const s16x8*)(hp + ct * 512);

    // QK^T (swapped): S'[j][q], log2 domain
    f32x4 st0 = {0,0,0,0}, st1 = {0,0,0,0};
    st0 = __builtin_amdgcn_mfma_f32_16x16x32_bf16(fr00, ga0, st0, 0, 0, 0);
    st0 = __builtin_amdgcn_mfma_f32_16x16x32_bf16(fr01, ga1, st0, 0, 0, 0);
    st1 = __builtin_amdgcn_mfma_f32_16x16x32_bf16(fr10, ga0, st1, 0, 0, 0);
    st1 = __builtin_amdgcn_mfma_f32_16x16x32_bf16(fr11, ga1, st1, 0, 0, 0);

    // prefetch f for next panel
    const int jn = (it < 63) ? jb + 1 : jb;
    const unsigned short* fnp = fMb + (size_t)(jn * 32 + l15) * 64 + 8 * sub;
    const s16x8 fn00 = *(const s16x8*)(fnp);
    const s16x8 fn01 = *(const s16x8*)(fnp + 32);
    const s16x8 fn10 = *(const s16x8*)(fnp + 1024);
    const s16x8 fn11 = *(const s16x8*)(fnp + 1024 + 32);

    // online softmax; defer-max THR=8
    float tmx = fmaxf(fmaxf(fmaxf(st0[0], st0[1]), fmaxf(st0[2], st0[3])),
                      fmaxf(fmaxf(st1[0], st1[1]), fmaxf(st1[2], st1[3])));
    tmx = fmaxf(tmx, __shfl_xor(tmx, 16));
    tmx = fmaxf(tmx, __shfl_xor(tmx, 32));
    float sc = 1.0f;
    if (__any(tmx > mrun + 8.0f)) {
      const float mn = fmaxf(mrun, tmx);
      sc = __builtin_amdgcn_exp2f(mrun - mn);
      mrun = mn; lsum *= sc;
    }
    float p0[4], p1[4];
#pragma unroll
    for (int v = 0; v < 4; ++v) {
      p0[v] = __builtin_amdgcn_exp2f(st0[v] - mrun);
      p1[v] = __builtin_amdgcn_exp2f(st1[v] - mrun);
    }
    float rs = (p0[0] + p0[1]) + (p0[2] + p0[3]) + (p1[0] + p1[1]) + (p1[2] + p1[3]);
    rs += __shfl_xor(rs, 16);
    rs += __shfl_xor(rs, 32);
    lsum += rs;

    const unsigned pk0 = cvt_pk_bf16(p0[0], p0[1]);
    const unsigned pk1 = cvt_pk_bf16(p0[2], p0[3]);
    const unsigned pk2 = cvt_pk_bf16(p1[0], p1[1]);
    const unsigned pk3 = cvt_pk_bf16(p1[2], p1[3]);
    *(u32x2*)&pb[qown * 16 + 2 * sub]     = (u32x2){pk0, pk1};
    *(u32x2*)&pb[qown * 16 + 8 + 2 * sub] = (u32x2){pk2, pk3};
    if (sub == 0) sc_arr[qown] = sc;
    __syncthreads();                     // P + scl ready (both streams in phase)

    // PV: rescale + 8 c-tiles x 4 q-tiles, h operand straight from registers
    float sc4[4];
#pragma unroll
    for (int qt = 0; qt < 4; ++qt) sc4[qt] = sc_arr[qt * 16 + l15];
    if (__any(fminf(fminf(sc4[0], sc4[1]), fminf(sc4[2], sc4[3])) < 1.0f)) {
#pragma unroll
      for (int ct = 0; ct < 8; ++ct)
#pragma unroll
        for (int qt = 0; qt < 4; ++qt) o[ct][qt] *= sc4[qt];
    }
#pragma unroll
    for (int qt = 0; qt < 4; ++qt) {
      const s16x8 pa = *(const s16x8*)((const unsigned short*)pb + (qt * 16 + l15) * 32 + sub * 8);
#pragma unroll
      for (int ct = 0; ct < 8; ++ct)
        o[ct][qt] = __builtin_amdgcn_mfma_f32_16x16x32_bf16(hreg[ct], pa, o[ct][qt], 0, 0, 0);
    }
    __syncthreads();                     // pbuf reads done before next write
    fr00 = fn00; fr01 = fn01; fr10 = fn10; fr11 = fn11;
  }

  // ---- merge the two streams + epilogue
  if (sub == 0) { mfin[s][qown] = mrun; lfin[s][qown] = lsum; }
  __syncthreads();
  const float gam = gamma[0];
  float* oldsS = (float*)(smem + s * 33024);   // stream's epilogue buffer [16][516] f32
  const float* oA = (const float*)smem;
  const float* oB = (const float*)(smem + 33024);
#pragma unroll
  for (int qt = 0; qt < 4; ++qt) {
    const int q = qt * 16 + l15;
    const float mA = mfin[0][q], mB = mfin[1][q];
    const float mm = fmaxf(mA, mB);
    const float eA = __builtin_amdgcn_exp2f(mA - mm);
    const float eB = __builtin_amdgcn_exp2f(mB - mm);
    const float Lt = lfin[0][q] * eA + lfin[1][q] * eB;
    const float fac = gam * ((s == 0) ? eA : eB) / Lt;
#pragma unroll
    for (int ct = 0; ct < 8; ++ct) {
      const f32x4 vv = o[ct][qt] * fac;
      *(f32x4*)&oldsS[l15 * 516 + ws * 128 + ct * 16 + 4 * sub] = vv;
    }
    __syncthreads();
    const int r = tid >> 5, c0 = (tid & 31) * 16;
    const float* xr  = x   + ((size_t)b * 4096 + qbase + qt * 16 + r) * 512;
    float*       orw = out + ((size_t)b * 4096 + qbase + qt * 16 + r) * 512;
#pragma unroll
    for (int i = 0; i < 4; ++i) {
      const int cc = c0 + i * 4;
      const f32x4 va = *(const f32x4*)&oA[r * 516 + cc];
      const f32x4 vb = *(const f32x4*)&oB[r * 516 + cc];
      const f32x4 xv = *(const f32x4*)(xr + cc);
      *(f32x4*)(orw + cc) = va + vb + xv;
    }
    __syncthreads();
  }
}

extern "C" void kernel_launch(void* const* d_in, const int* in_sizes, int n_in,
                              void* d_out, int out_size, void* d_ws, size_t ws_size,
                              hipStream_t stream) {
  const float* x     = (const float*)d_in[0];
  const float* kf    = (const float*)d_in[1];
  const float* kg    = (const float*)d_in[2];
  const float* kh    = (const float*)d_in[3];
  const float* bf    = (const float*)d_in[4];
  const float* bg    = (const float*)d_in[5];
  const float* bh    = (const float*)d_in[6];
  const float* gamma = (const float*)d_in[7];
  float* out = (float*)d_out;

  char* ws = (char*)d_ws;
  unsigned short* fO = (unsigned short*)(ws);
  unsigned short* gO = (unsigned short*)(ws + (2u << 20));
  unsigned short* hP = (unsigned short*)(ws + (4u << 20));
  unsigned short* wT = (unsigned short*)(ws + (20u << 20));

  hipLaunchKernelGGL(wt_kernel,   dim3(640), dim3(256), 0, stream, kf, kg, kh, wT);
  hipLaunchKernelGGL(gemm_kernel, dim3(256), dim3(256), 0, stream,
                     x, wT, bf, bg, bh, fO, gO, hP);
  hipLaunchKernelGGL(attn_kernel, dim3(256), dim3(512), 0, stream,
                     fO, gO, hP, x, gamma, out);
}